// Round 8
// baseline (275.282 us; speedup 1.0000x reference)
//
#include <hip/hip_runtime.h>
#include <stdint.h>

#define NUM_EXPERT 8
#define IN_FEAT 1024
#define OUT_FEAT 4096
#define N_TOKENS 4096

#define BM 128
#define BN 128
#define BK 64
#define MAX_ROW_TILES 40      // worst-case sum_e ceil(cnt_e/128)

// conv: each block converts 32 KB fp32 -> 16 KB bf16 (256 thr x 4 pairs).
// inp: 16 MB -> 512 blocks; weight: 128 MB -> 4096 blocks; +1 sort (bid 0).
#define CONV_BLKS_INP 512
#define CONV_BLKS_W   4096
#define PREP_BLKS (CONV_BLKS_INP + CONV_BLKS_W + 1)   // 4609

typedef __attribute__((ext_vector_type(8))) short short8;   // 8 x bf16 bits
typedef __attribute__((ext_vector_type(4))) float f32x4;

__device__ __forceinline__ void async_cp16(const void* g, void* l) {
    __builtin_amdgcn_global_load_lds(
        (const __attribute__((address_space(1))) void*)g,
        (__attribute__((address_space(3))) void*)l, 16, 0, 0);
}

__device__ __forceinline__ unsigned int cvtpk(float lo, float hi) {
    // 2 fp32 -> 2 bf16 (RNE), packed: lo -> bits[15:0], hi -> bits[31:16]
    unsigned int r;
    asm("v_cvt_pk_bf16_f32 %0, %1, %2" : "=v"(r) : "v"(lo), "v"(hi));
    return r;
}

// ---------------- Kernel 1: prep = sort (block 0) + fp32->bf16 cvt -----------
// Converter: inline-asm forced depth-8 MLP. Every prior variant (R0 branchy,
// R5 reg-batch, R7 DMA+LDS) measured ~2.7 TB/s effective; counters showed the
// compiler (VGPR 40 = ~2 loads in flight) or my LDS cap (2 blk/CU) limited
// outstanding bytes/CU to ~15 GB/s/CU. asm volatile pins 8 loads in flight
// per thread with no LDS -> ~32 waves/CU x 128 B = 256 KB/CU outstanding.
// Drain: descending counted vmcnt (stores are newer; waits never block on
// them): before wait c, queue = (8-2c) loads + c stores; vmcnt(6-c) retires
// exactly loads 2c,2c+1. sched_barrier(0) per rule #18.
// meta layout (int): [0..7]=cnt, [8..15]=off, [16..16+4096)=perm
__global__ __launch_bounds__(256)
void moe_prep(const float* __restrict__ inp_f,
              const int* __restrict__ gate,
              const float* __restrict__ weight_f,
              unsigned short* __restrict__ wsA,
              unsigned short* __restrict__ wsB,
              int* __restrict__ meta) {
    const int tid = threadIdx.x;
    const int bid = blockIdx.x;

    if (bid == 0) {
        // ---------------- sort: one block, validated logic ----------------
        __shared__ int cnt[NUM_EXPERT];
        __shared__ int off[NUM_EXPERT];
        __shared__ int wsum[4];
        const int lane = tid & 63;
        const int wave = tid >> 6;

        int gv[16];
        const int4* gp = (const int4*)(gate + tid * 16);
#pragma unroll
        for (int i = 0; i < 4; ++i) {
            int4 v = gp[i];
            gv[i * 4 + 0] = v.x; gv[i * 4 + 1] = v.y;
            gv[i * 4 + 2] = v.z; gv[i * 4 + 3] = v.w;
        }
        int lc[NUM_EXPERT];
#pragma unroll
        for (int e = 0; e < NUM_EXPERT; ++e) {
            int c = 0;
#pragma unroll
            for (int j = 0; j < 16; ++j) c += (gv[j] == e) ? 1 : 0;
            lc[e] = c;
        }
        if (tid < NUM_EXPERT) cnt[tid] = 0;
        __syncthreads();
#pragma unroll
        for (int e = 0; e < NUM_EXPERT; ++e) {
            int c = lc[e];
#pragma unroll
            for (int d = 32; d > 0; d >>= 1) c += __shfl_down(c, d);
            if (lane == 0 && c) atomicAdd(&cnt[e], c);
        }
        __syncthreads();
        if (tid == 0) {
            int a = 0;
#pragma unroll
            for (int e = 0; e < NUM_EXPERT; ++e) { off[e] = a; a += cnt[e]; }
        }
        __syncthreads();
        if (tid < NUM_EXPERT) { meta[tid] = cnt[tid]; meta[8 + tid] = off[tid]; }

        int* perm = meta + 16;
#pragma unroll
        for (int e = 0; e < NUM_EXPERT; ++e) {
            int c_t = lc[e];
            int inc = c_t;
#pragma unroll
            for (int d = 1; d < 64; d <<= 1) {
                int t = __shfl_up(inc, d);
                if (lane >= d) inc += t;
            }
            if (lane == 63) wsum[wave] = inc;
            __syncthreads();
            int base = off[e];
#pragma unroll
            for (int w = 0; w < 4; ++w) if (w < wave) base += wsum[w];
            int rank = base + inc - c_t;
#pragma unroll
            for (int j = 0; j < 16; ++j) {
                if (gv[j] == e) { perm[rank] = tid * 16 + j; rank++; }
            }
            __syncthreads();
        }
    } else {
        // ---------------- converter: 32 KB fp32 -> 16 KB bf16 per block ----
        const char* src; char* dst;
        if (bid <= CONV_BLKS_INP) {
            int lb = bid - 1;
            src = (const char*)inp_f + (size_t)lb * 32768;
            dst = (char*)wsA + (size_t)lb * 16384;
        } else {
            int lb = bid - 1 - CONV_BLKS_INP;
            src = (const char*)weight_f + (size_t)lb * 32768;
            dst = (char*)wsB + (size_t)lb * 16384;
        }

        // pair p = c*256 + tid (c=0..3): read 32 B at p*32, write 16 B at p*16
        float4 v0, v1, v2, v3, v4, v5, v6, v7;
        const char* a0 = src + (size_t)tid * 32;             // + c*8192
        asm volatile("global_load_dwordx4 %0, %1, off"           : "=&v"(v0) : "v"(a0));
        asm volatile("global_load_dwordx4 %0, %1, off offset:16" : "=&v"(v1) : "v"(a0));
        const char* a1 = a0 + 8192;
        asm volatile("global_load_dwordx4 %0, %1, off"           : "=&v"(v2) : "v"(a1));
        asm volatile("global_load_dwordx4 %0, %1, off offset:16" : "=&v"(v3) : "v"(a1));
        const char* a2 = a0 + 16384;
        asm volatile("global_load_dwordx4 %0, %1, off"           : "=&v"(v4) : "v"(a2));
        asm volatile("global_load_dwordx4 %0, %1, off offset:16" : "=&v"(v5) : "v"(a2));
        const char* a3 = a0 + 24576;
        asm volatile("global_load_dwordx4 %0, %1, off"           : "=&v"(v6) : "v"(a3));
        asm volatile("global_load_dwordx4 %0, %1, off offset:16" : "=&v"(v7) : "v"(a3));

        char* dw = dst + (size_t)tid * 16;                   // + c*4096

        asm volatile("s_waitcnt vmcnt(6)" ::: "memory");
        __builtin_amdgcn_sched_barrier(0);
        {
            uint4 o;
            o.x = cvtpk(v0.x, v0.y); o.y = cvtpk(v0.z, v0.w);
            o.z = cvtpk(v1.x, v1.y); o.w = cvtpk(v1.z, v1.w);
            *(uint4*)(dw) = o;
        }
        asm volatile("s_waitcnt vmcnt(5)" ::: "memory");
        __builtin_amdgcn_sched_barrier(0);
        {
            uint4 o;
            o.x = cvtpk(v2.x, v2.y); o.y = cvtpk(v2.z, v2.w);
            o.z = cvtpk(v3.x, v3.y); o.w = cvtpk(v3.z, v3.w);
            *(uint4*)(dw + 4096) = o;
        }
        asm volatile("s_waitcnt vmcnt(4)" ::: "memory");
        __builtin_amdgcn_sched_barrier(0);
        {
            uint4 o;
            o.x = cvtpk(v4.x, v4.y); o.y = cvtpk(v4.z, v4.w);
            o.z = cvtpk(v5.x, v5.y); o.w = cvtpk(v5.z, v5.w);
            *(uint4*)(dw + 8192) = o;
        }
        asm volatile("s_waitcnt vmcnt(3)" ::: "memory");
        __builtin_amdgcn_sched_barrier(0);
        {
            uint4 o;
            o.x = cvtpk(v6.x, v6.y); o.y = cvtpk(v6.z, v6.w);
            o.z = cvtpk(v7.x, v7.y); o.w = cvtpk(v7.z, v7.w);
            *(uint4*)(dw + 12288) = o;
        }
    }
}

// ---------------- Kernel 2: bf16 grouped GEMM, LDS = exactly 32 KB -----------
// C[tok][n] = sum_k inp[tok][k] * W[e][n][k]   (both operands K-contiguous)
// Proven kernel: global_load_lds DMA staging, XOR-swizzled LDS, high residency.
// NOTE: plain __launch_bounds__(256). A (256,5) min-waves hint forced VGPR
// 92->48 and spilled the accumulator to scratch (3.5x slower).
__global__ __launch_bounds__(256)
void moe_gemm_bf16(const unsigned short* __restrict__ inp,
                   const unsigned short* __restrict__ weight,
                   const int* __restrict__ meta,
                   float* __restrict__ out) {
    __shared__ __align__(16) unsigned short As[BM * BK];   // 16 KB
    __shared__ __align__(16) unsigned short Bs[BN * BK];   // 16 KB  (total 32768 B)

    const int* cnt  = meta;
    const int* off  = meta + 8;
    const int* perm = meta + 16;

    // ---- map blockIdx.y -> (expert, local row-tile); block-uniform ----
    int local = blockIdx.y;
    int e = -1, grp_cnt = 0, grp_off = 0;
#pragma unroll
    for (int i = 0; i < NUM_EXPERT; ++i) {
        int c = cnt[i];
        int t = (c + BM - 1) >> 7;
        if (e < 0) {
            if (local < t) { e = i; grp_cnt = c; grp_off = off[i]; }
            else           local -= t;
        }
    }
    if (e < 0) return;

    const int n0   = blockIdx.x * BN;
    const int row0 = local * BM;
    int vcnt = grp_cnt - row0; if (vcnt > BM) vcnt = BM;

    const int tid  = threadIdx.x;
    const int lane = tid & 63;
    const int wave = tid >> 6;

    // ---- staging descriptors: thread stages chunks c = i*256+tid (16 B each).
    // LDS slot (row=c>>3, kcp=c&7) receives global chunk kc = kcp ^ (row&7).
    const char* ag[4]; const char* bg[4];
    char* al[4]; char* bl[4];
    const char* inp_b = (const char*)inp;
    const char* w_b   = (const char*)weight + (size_t)e * (size_t)(OUT_FEAT * IN_FEAT) * 2;
#pragma unroll
    for (int i = 0; i < 4; ++i) {
        int c   = i * 256 + tid;
        int row = c >> 3;
        int kc  = (c & 7) ^ (row & 7);
        int p   = row0 + row; if (p > grp_cnt - 1) p = grp_cnt - 1;  // clamp tail
        int tok = perm[grp_off + p];
        ag[i] = inp_b + (size_t)tok * (IN_FEAT * 2) + kc * 16;
        bg[i] = w_b   + (size_t)(n0 + row) * (IN_FEAT * 2) + kc * 16;
        al[i] = (char*)As + c * 16;
        bl[i] = (char*)Bs + c * 16;
    }

    // ---- fragment LDS byte offsets: row*128 + ((ks*4+quad)^(row&7))*16 ----
    const int wm   = (wave & 1) * 64;
    const int wn   = (wave >> 1) * 64;
    const int lcol = lane & 15;
    const int quad = lane >> 4;

    int aoff[2][4], boff[2][4];
#pragma unroll
    for (int ks = 0; ks < 2; ++ks)
#pragma unroll
        for (int t = 0; t < 4; ++t) {
            int ra = wm + t * 16 + lcol;
            aoff[ks][t] = ra * 128 + (((ks * 4 + quad) ^ (ra & 7)) * 16);
            int rb = wn + t * 16 + lcol;
            boff[ks][t] = rb * 128 + (((ks * 4 + quad) ^ (rb & 7)) * 16);
        }

    const f32x4 vzero = {0.f, 0.f, 0.f, 0.f};
    f32x4 acc[4][4];
#pragma unroll
    for (int i = 0; i < 4; ++i)
#pragma unroll
        for (int j = 0; j < 4; ++j) acc[i][j] = vzero;

    const char* As_b = (const char*)As;
    const char* Bs_b = (const char*)Bs;

    for (int k0 = 0; k0 < IN_FEAT; k0 += BK) {
#pragma unroll
        for (int i = 0; i < 4; ++i) { async_cp16(ag[i], al[i]); ag[i] += BK * 2; }
#pragma unroll
        for (int i = 0; i < 4; ++i) { async_cp16(bg[i], bl[i]); bg[i] += BK * 2; }
        __builtin_amdgcn_s_waitcnt(0);   // drain global_load_lds before barrier
        __syncthreads();
#pragma unroll
        for (int ks = 0; ks < 2; ++ks) {
            short8 af[4], bf[4];
#pragma unroll
            for (int im = 0; im < 4; ++im) af[im] = *(const short8*)(As_b + aoff[ks][im]);
#pragma unroll
            for (int jn = 0; jn < 4; ++jn) bf[jn] = *(const short8*)(Bs_b + boff[ks][jn]);
#pragma unroll
            for (int im = 0; im < 4; ++im)
#pragma unroll
                for (int jn = 0; jn < 4; ++jn)
                    acc[im][jn] = __builtin_amdgcn_mfma_f32_16x16x32_bf16(
                        af[im], bf[jn], acc[im][jn], 0, 0, 0);
        }
        __syncthreads();
    }

    // ---- epilogue: C/D layout col=lane&15, row=quad*4+reg; fp32 scatter ----
#pragma unroll
    for (int im = 0; im < 4; ++im) {
#pragma unroll
        for (int reg = 0; reg < 4; ++reg) {
            int r = wm + im * 16 + quad * 4 + reg;
            if (r < vcnt) {
                int tok = perm[grp_off + row0 + r];
                float* orow = out + (size_t)tok * OUT_FEAT + (n0 + wn + lcol);
#pragma unroll
                for (int jn = 0; jn < 4; ++jn)
                    orow[jn * 16] = acc[im][jn][reg];
            }
        }
    }
}

extern "C" void kernel_launch(void* const* d_in, const int* in_sizes, int n_in,
                              void* d_out, int out_size, void* d_ws, size_t ws_size,
                              hipStream_t stream) {
    const float* inp    = (const float*)d_in[0];   // fp32 [4096,1024]
    const int*   gate   = (const int*)d_in[1];     // int32 [4096]
    const float* weight = (const float*)d_in[2];   // fp32 [8,4096,1024]
    float*       out    = (float*)d_out;           // fp32 [4096,4096]
    (void)in_sizes; (void)n_in; (void)out_size; (void)ws_size;

    const size_t n_inp = (size_t)N_TOKENS * IN_FEAT;                 // 4M elems
    const size_t n_w   = (size_t)NUM_EXPERT * OUT_FEAT * IN_FEAT;    // 32M elems

    unsigned short* wsA  = (unsigned short*)d_ws;        // 8 MB bf16 inp
    unsigned short* wsB  = wsA + n_inp;                  // 64 MB bf16 weight
    int*            meta = (int*)(wsB + n_w);            // cnt/off/perm (~16.5 KB)

    moe_prep<<<PREP_BLKS, 256, 0, stream>>>(inp, gate, weight, wsA, wsB, meta);
    dim3 grid(OUT_FEAT / BN, MAX_ROW_TILES);
    moe_gemm_bf16<<<grid, 256, 0, stream>>>(wsA, wsB, meta, out);
}